// Round 19
// baseline (18.592 us; speedup 1.0000x reference)
//
#include <hip/hip_runtime.h>
#include <hip/hip_fp16.h>
#include <math.h>

#define N_G   4096
#define CAP   1024
#define W_IMG 256
#define H_IMG 256

// ---------- kernel 1: project once, packed unsorted outputs ----------
// pkU[i] = { char4 tile-unit bbox (packed int), depth_bits } : one 8B load
// serves both the cull test and the sort key.
__global__ __launch_bounds__(64) void prep(
    const float* __restrict__ pos, const float* __restrict__ scl,
    const float* __restrict__ rot, const float* __restrict__ col,
    const float* __restrict__ opa, const float* __restrict__ vm,
    float4* __restrict__ gaussU, short4* __restrict__ bbhU,
    int2* __restrict__ pkU)
{
  const int i = blockIdx.x * 64 + threadIdx.x;
  if (i >= N_G) return;
  const float FX=300.f, FY=300.f, CXc=128.f, CYc=128.f;
  const float HLOG2E = 0.72134752f;     // 0.5*log2(e)
  float V00=vm[0],V01=vm[1],V02=vm[2],V03=vm[3];
  float V10=vm[4],V11=vm[5],V12=vm[6],V13=vm[7];
  float V20=vm[8],V21=vm[9],V22=vm[10],V23=vm[11];
  float p0=pos[3*i], p1=pos[3*i+1], p2=pos[3*i+2];
  float X = V00*p0+V01*p1+V02*p2+V03;
  float Y = V10*p0+V11*p1+V12*p2+V13;
  float Z = V20*p0+V21*p1+V22*p2+V23;
  float depth = -Z;
  float zp = Z + 1e-8f;
  float sgn = (zp>0.f)?1.f:((zp<0.f)?-1.f:0.f);
  float z_safe = fmaxf(fabsf(Z), 0.01f) * sgn;
  float z2 = z_safe*z_safe;
  float qw=rot[4*i], qx=rot[4*i+1], qy=rot[4*i+2], qz=rot[4*i+3];
  float qi = 1.f/sqrtf(qw*qw+qx*qx+qy*qy+qz*qz);
  qw*=qi; qx*=qi; qy*=qi; qz*=qi;
  float R00=1.f-2.f*qy*qy-2.f*qz*qz, R01=2.f*qx*qy-2.f*qw*qz, R02=2.f*qx*qz+2.f*qw*qy;
  float R10=2.f*qx*qy+2.f*qw*qz, R11=1.f-2.f*qx*qx-2.f*qz*qz, R12=2.f*qy*qz-2.f*qw*qx;
  float R20=2.f*qx*qz-2.f*qw*qy, R21=2.f*qy*qz+2.f*qw*qx, R22=1.f-2.f*qx*qx-2.f*qy*qy;
  float C00=V00*R00+V01*R10+V02*R20, C01=V00*R01+V01*R11+V02*R21, C02=V00*R02+V01*R12+V02*R22;
  float C10=V10*R00+V11*R10+V12*R20, C11=V10*R01+V11*R11+V12*R21, C12=V10*R02+V11*R12+V12*R22;
  float C20=V20*R00+V21*R10+V22*R20, C21=V20*R01+V21*R11+V22*R21, C22=V20*R02+V21*R12+V22*R22;
  float s0=scl[3*i], s1=scl[3*i+1], s2=scl[3*i+2];
  float S00=C00*s0,S01=C01*s1,S02=C02*s2;
  float S10=C10*s0,S11=C11*s1,S12=C12*s2;
  float S20=C20*s0,S21=C21*s1,S22=C22*s2;
  float c00=S00*S00+S01*S01+S02*S02;
  float c01=S00*S10+S01*S11+S02*S12;
  float c02=S00*S20+S01*S21+S02*S22;
  float c11=S10*S10+S11*S11+S12*S12;
  float c12=S10*S20+S11*S21+S12*S22;
  float c22=S20*S20+S21*S21+S22*S22;
  float j00=FX/(-z_safe), j02=FX*X/z2;
  float j11=FY/z_safe,    j12=FY*Y/z2;
  float M00=j00*c00+j02*c02, M01=j00*c01+j02*c12, M02=j00*c02+j02*c22;
  float M10=j11*c01+j12*c02, M11=j11*c11+j12*c12, M12=j11*c12+j12*c22;
  float a =M00*j00+M02*j02;
  float b =M01*j11+M02*j12;
  float c_=M10*j00+M12*j02;
  float d =M11*j11+M12*j12;
  float u = FX*X/(-z_safe)+CXc;
  float v = FY*(-Y)/(-z_safe)+CYc;
  float tr=a+d;
  float det=fmaxf(a*d-b*c_, 1e-6f);
  float disc=fmaxf(tr*tr-4.f*det, 0.f);
  float lam=(tr+sqrtf(disc))*0.5f;
  float radius=fminf(3.f*sqrtf(fmaxf(lam,1e-6f)), 64.f);
  bool vis = (depth>0.01f)&&(depth<100.f)
          && (u+radius>0.f)&&(u-radius<(float)W_IMG)
          && (v+radius>0.f)&&(v-radius<(float)H_IMG);
  float o = vis ? opa[i] : 0.f;
  float ar=a+1e-4f, dr=d+1e-4f;
  float inv=1.f/(ar*dr-b*c_);
  short4 bb = make_short4(1000, -1000, 1000, -1000);    // sentinel: no hit
  int btp = (127 & 0xFF) | ((-128 & 0xFF)<<8) | ((127 & 0xFF)<<16) | (-128<<24);
  if (o>0.f) {
    bb.x=(short)truncf(u-radius); bb.y=(short)truncf(u+radius);
    bb.z=(short)truncf(v-radius); bb.w=(short)truncf(v+radius);
    int tx0=((int)bb.x)>>3, tx1=((int)bb.y)>>3;
    int ty0=((int)bb.z)>>3, ty1=((int)bb.w)>>3;
    btp = (tx0 & 0xFF) | ((tx1 & 0xFF)<<8) | ((ty0 & 0xFF)<<16) | (ty1<<24);
  }
  unsigned hrg = (unsigned)__half_as_ushort(__float2half_rn(col[3*i]))
               | ((unsigned)__half_as_ushort(__float2half_rn(col[3*i+1]))<<16);
  bbhU[i]   = bb;
  pkU[i]    = make_int2(btp, (int)__float_as_uint(depth));
  gaussU[2*i]   = make_float4(u, v, (dr*inv)*HLOG2E,
                              ((-b*inv)+(-c_*inv))*HLOG2E);
  gaussU[2*i+1] = make_float4((ar*inv)*HLOG2E, log2f(o),
                              __uint_as_float(hrg), col[3*i+2]);
}

// ---- kernel 2: single-pass cull (8B packed) + split rank + composite ----
// Block = 16x8 region (2 tiles of 8x8), 16 waves, 2 blocks/CU. R18 champion
// + (a) one int2 load per gaussian in cull (tile-bbox + depth_bits packed),
// (b) 2x-split all-pairs rank (workers tid / tid+512) when len<=512 —
// halves the rank serial chain using the otherwise-idle waves 8-15.
__global__ __launch_bounds__(1024) void render(
    const int2* __restrict__ pkU, const short4* __restrict__ bbhU,
    const float4* __restrict__ gaussU, float* __restrict__ out)
{
  __shared__ __align__(16) unsigned long long keys[CAP];    // 8 KB
  __shared__ float4 gp[CAP*2];                              // 32 KB
  __shared__ short4 bbh[CAP];                               // 8 KB
  __shared__ float4 res[16][64];                            // 16 KB
  __shared__ int lcnt;
  int* pr = (int*)res;     // partial ranks; res not live until composite

  const int tid = threadIdx.x, wv = tid>>6, lane = tid&63;
  const int bid = (int)((blockIdx.x * 331u) & 511u);   // spread heavy regions
  const int RX0=(bid&15)*16, RY0=(bid>>4)*8;
  const int rtx0=RX0>>3, rtx1=(RX0+15)>>3, rty=RY0>>3;

  if (tid==0) lcnt=0;
  __syncthreads();

  // ---- cull: 16 waves x 4 chunks; one 8B load/gaussian, then
  //      ballot-aggregated LDS-atomic scatter (keys from registers) ----
  {
    int2 pk[4];
    #pragma unroll
    for (int c4=0;c4<4;c4++) pk[c4]=pkU[(wv*4+c4)*64+lane];
    #pragma unroll
    for (int c4=0;c4<4;c4++) {
      int idx=(wv*4+c4)*64+lane;
      int w=pk[c4].x;
      int bx=(int)(signed char)(w);
      int by=(int)(signed char)(w>>8);
      int bz=(int)(signed char)(w>>16);
      int bw_=(w>>24);                       // arithmetic shift keeps sign
      bool pred=(by>=rtx0)&&(bx<=rtx1)&&(bw_>=rty)&&(bz<=rty);
      unsigned long long m=__ballot(pred);
      if (m) {
        int bse=0;
        if (lane==0) bse=atomicAdd(&lcnt, __popcll(m));
        bse=__shfl(bse,0);
        if (pred) {
          int p=bse+__popcll(m&((1ull<<lane)-1ull));
          if (p<CAP)
            keys[p]=((unsigned long long)(unsigned)pk[c4].y<<12)
                   |(unsigned)idx;
        }
      }
    }
  }
  __syncthreads();
  const int len = (lcnt<CAP)?lcnt:CAP;
  const bool split = (len<=512);             // block-uniform

  // ---- stable rank (+gather loads issued early by worker A) ----
  if (split) {
    const ulonglong2* k2=(const ulonglong2*)keys;
    const int n2=len>>1, nA=n2>>1;
    float4 g0, g1; short4 b0;
    if (tid<len) {                           // worker A: first half + loads
      unsigned long long kj=keys[tid];
      int idx=(int)(kj&4095u);
      g0=gaussU[2*idx];                      // L2 latency hides under loop
      g1=gaussU[2*idx+1];
      b0=bbhU[idx];
      int r=0;
      for(int s2=0;s2<nA;s2++){ ulonglong2 kv=k2[s2]; r+=(kv.x<kj)+(kv.y<kj); }
      pr[tid]=r;
    } else if (tid>=512 && tid-512<len) {    // worker B: second half
      int j=tid-512;
      unsigned long long kj=keys[j];
      int r=0;
      for(int s2=nA;s2<n2;s2++){ ulonglong2 kv=k2[s2]; r+=(kv.x<kj)+(kv.y<kj); }
      if(len&1) r += (keys[len-1]<kj);
      pr[tid]=r;
    }
    __syncthreads();
    if (tid<len) {
      int r=pr[tid]+pr[512+tid];
      gp[2*r]  =g0;
      gp[2*r+1]=g1;
      bbh[r]   =b0;
    }
  } else {
    if (tid<len) {
      unsigned long long kj=keys[tid];
      int idx=(int)(kj&4095u);
      float4 g0=gaussU[2*idx];
      float4 g1=gaussU[2*idx+1];
      short4 b0=bbhU[idx];
      int r=0;
      const ulonglong2* k2=(const ulonglong2*)keys;
      int n2=len>>1;
      for(int s2=0;s2<n2;s2++){ ulonglong2 kv=k2[s2]; r+=(kv.x<kj)+(kv.y<kj); }
      if(len&1) r += (keys[len-1]<kj);
      gp[2*r]  =g0;
      gp[2*r+1]=g1;
      bbh[r]   =b0;
    }
  }
  __syncthreads();

  // ---- composite: wave w -> tile t=w>>3, depth-segment s=w&7 ----
  const int t=wv>>3, seg=wv&7;
  const int TX0=RX0+t*8, TY0=RY0, TX1=TX0+7, TY1=TY0+7;
  const int ipx=TX0+(lane&7), ipy=TY0+(lane>>3);
  const float px=(float)ipx, py=(float)ipy;
  const int segLen=(len+7)>>3;
  const int s=seg*segLen;
  int e=s+segLen; if(e>len) e=len;
  float aR=0.f,aG=0.f,aB=0.f,aA=0.f;
  for(int k0=s;k0<e;k0+=64){
    int kk=k0+lane;
    bool ok=false;
    if(kk<e){
      short4 bb=bbh[kk];
      ok=(bb.y>=TX0)&&(bb.x<=TX1)&&(bb.w>=TY0)&&(bb.z<=TY1);
    }
    unsigned long long mm=__ballot(ok);     // tile compaction, order-kept
    if(mm){
      int k=k0+__builtin_ctzll(mm); mm&=mm-1;
      short4 bb=bbh[k];                     // current (broadcast)
      float4 A=gp[2*k], B=gp[2*k+1];
      while(mm){
        int kn=k0+__builtin_ctzll(mm); mm&=mm-1;
        short4 bbn=bbh[kn];                 // prefetch next while computing
        float4 An=gp[2*kn], Bn=gp[2*kn+1];
        float dx=px-A.x, dy=py-A.y;
        float q2=A.z*dx*dx + A.w*dx*dy + B.x*dy*dy;
        bool inside=(ipx>=bb.x)&&(ipx<=bb.y)&&(ipy>=bb.z)&&(ipy<=bb.w);
        float ex=__builtin_amdgcn_exp2f(B.y-q2);
        float alpha= inside ? ex : 0.f;
        float w=alpha*(1.f-aA);
        unsigned hrg=__float_as_uint(B.z);
        float cR=__half2float(__ushort_as_half((unsigned short)(hrg&0xFFFFu)));
        float cG=__half2float(__ushort_as_half((unsigned short)(hrg>>16)));
        aR+=w*cR; aG+=w*cG; aB+=w*B.w; aA+=w;
        bb=bbn; A=An; B=Bn;
      }
      float dx=px-A.x, dy=py-A.y;
      float q2=A.z*dx*dx + A.w*dx*dy + B.x*dy*dy;
      bool inside=(ipx>=bb.x)&&(ipx<=bb.y)&&(ipy>=bb.z)&&(ipy<=bb.w);
      float ex=__builtin_amdgcn_exp2f(B.y-q2);
      float alpha= inside ? ex : 0.f;
      float w=alpha*(1.f-aA);
      unsigned hrg=__float_as_uint(B.z);
      float cR=__half2float(__ushort_as_half((unsigned short)(hrg&0xFFFFu)));
      float cG=__half2float(__ushort_as_half((unsigned short)(hrg>>16)));
      aR+=w*cR; aG+=w*cG; aB+=w*B.w; aA+=w;
    }
    if(__ballot(aA<=0.9999f)==0ull) break;  // residual < 1e-4
  }
  res[wv][lane]=make_float4(aR,aG,aB,aA);
  __syncthreads();

  // ---- ordered 8-way fold per tile, store ----
  if(seg==0){
    float4 P=res[wv][lane];
    #pragma unroll
    for(int w=1;w<8;w++){
      float4 Q=res[wv+w][lane];
      float tr_=1.f-P.w;
      P.x+=tr_*Q.x; P.y+=tr_*Q.y; P.z+=tr_*Q.z; P.w+=tr_*Q.w;
    }
    out[0*H_IMG*W_IMG + ipy*W_IMG + ipx]=P.x;
    out[1*H_IMG*W_IMG + ipy*W_IMG + ipx]=P.y;
    out[2*H_IMG*W_IMG + ipy*W_IMG + ipx]=P.z;
  }
}

extern "C" void kernel_launch(void* const* d_in, const int* in_sizes, int n_in,
                              void* d_out, int out_size, void* d_ws, size_t ws_size,
                              hipStream_t stream)
{
  const float* pos=(const float*)d_in[0];
  const float* scl=(const float*)d_in[1];
  const float* rot=(const float*)d_in[2];
  const float* col=(const float*)d_in[3];
  const float* opa=(const float*)d_in[4];
  const float* vm =(const float*)d_in[5];
  float* out=(float*)d_out;
  char* ws=(char*)d_ws;
  float4* gaussU=(float4*)(ws);               // 128 KB
  short4* bbhU  =(short4*)(ws + 128*1024);    // 32 KB
  int2*   pkU   =(int2*)  (ws + 160*1024);    // 32 KB
  prep<<<N_G/64, 64, 0, stream>>>(pos,scl,rot,col,opa,vm,gaussU,bbhU,pkU);
  render<<<512, 1024, 0, stream>>>(pkU,bbhU,gaussU,out);
}

// Round 20
// 18.218 us; speedup vs baseline: 1.0205x; 1.0205x over previous
//
#include <hip/hip_runtime.h>
#include <hip/hip_fp16.h>
#include <math.h>

#define N_G   4096
#define CAP   1024
#define W_IMG 256
#define H_IMG 256

// ---------- kernel 1: project once, packed unsorted outputs ----------
__global__ __launch_bounds__(64) void prep(
    const float* __restrict__ pos, const float* __restrict__ scl,
    const float* __restrict__ rot, const float* __restrict__ col,
    const float* __restrict__ opa, const float* __restrict__ vm,
    float4* __restrict__ gaussU, short4* __restrict__ bbhU,
    float* __restrict__ depthU, char4* __restrict__ bbtU)
{
  const int i = blockIdx.x * 64 + threadIdx.x;
  if (i >= N_G) return;
  const float FX=300.f, FY=300.f, CXc=128.f, CYc=128.f;
  const float HLOG2E = 0.72134752f;     // 0.5*log2(e)
  float V00=vm[0],V01=vm[1],V02=vm[2],V03=vm[3];
  float V10=vm[4],V11=vm[5],V12=vm[6],V13=vm[7];
  float V20=vm[8],V21=vm[9],V22=vm[10],V23=vm[11];
  float p0=pos[3*i], p1=pos[3*i+1], p2=pos[3*i+2];
  float X = V00*p0+V01*p1+V02*p2+V03;
  float Y = V10*p0+V11*p1+V12*p2+V13;
  float Z = V20*p0+V21*p1+V22*p2+V23;
  float depth = -Z;
  float zp = Z + 1e-8f;
  float sgn = (zp>0.f)?1.f:((zp<0.f)?-1.f:0.f);
  float z_safe = fmaxf(fabsf(Z), 0.01f) * sgn;
  float z2 = z_safe*z_safe;
  float qw=rot[4*i], qx=rot[4*i+1], qy=rot[4*i+2], qz=rot[4*i+3];
  float qi = 1.f/sqrtf(qw*qw+qx*qx+qy*qy+qz*qz);
  qw*=qi; qx*=qi; qy*=qi; qz*=qi;
  float R00=1.f-2.f*qy*qy-2.f*qz*qz, R01=2.f*qx*qy-2.f*qw*qz, R02=2.f*qx*qz+2.f*qw*qy;
  float R10=2.f*qx*qy+2.f*qw*qz, R11=1.f-2.f*qx*qx-2.f*qz*qz, R12=2.f*qy*qz-2.f*qw*qx;
  float R20=2.f*qx*qz-2.f*qw*qy, R21=2.f*qy*qz+2.f*qw*qx, R22=1.f-2.f*qx*qx-2.f*qy*qy;
  float C00=V00*R00+V01*R10+V02*R20, C01=V00*R01+V01*R11+V02*R21, C02=V00*R02+V01*R12+V02*R22;
  float C10=V10*R00+V11*R10+V12*R20, C11=V10*R01+V11*R11+V12*R21, C12=V10*R02+V11*R12+V12*R22;
  float C20=V20*R00+V21*R10+V22*R20, C21=V20*R01+V21*R11+V22*R21, C22=V20*R02+V21*R12+V22*R22;
  float s0=scl[3*i], s1=scl[3*i+1], s2=scl[3*i+2];
  float S00=C00*s0,S01=C01*s1,S02=C02*s2;
  float S10=C10*s0,S11=C11*s1,S12=C12*s2;
  float S20=C20*s0,S21=C21*s1,S22=C22*s2;
  float c00=S00*S00+S01*S01+S02*S02;
  float c01=S00*S10+S01*S11+S02*S12;
  float c02=S00*S20+S01*S21+S02*S22;
  float c11=S10*S10+S11*S11+S12*S12;
  float c12=S10*S20+S11*S21+S12*S22;
  float c22=S20*S20+S21*S21+S22*S22;
  float j00=FX/(-z_safe), j02=FX*X/z2;
  float j11=FY/z_safe,    j12=FY*Y/z2;
  float M00=j00*c00+j02*c02, M01=j00*c01+j02*c12, M02=j00*c02+j02*c22;
  float M10=j11*c01+j12*c02, M11=j11*c11+j12*c12, M12=j11*c12+j12*c22;
  float a =M00*j00+M02*j02;
  float b =M01*j11+M02*j12;
  float c_=M10*j00+M12*j02;
  float d =M11*j11+M12*j12;
  float u = FX*X/(-z_safe)+CXc;
  float v = FY*(-Y)/(-z_safe)+CYc;
  float tr=a+d;
  float det=fmaxf(a*d-b*c_, 1e-6f);
  float disc=fmaxf(tr*tr-4.f*det, 0.f);
  float lam=(tr+sqrtf(disc))*0.5f;
  float radius=fminf(3.f*sqrtf(fmaxf(lam,1e-6f)), 64.f);
  bool vis = (depth>0.01f)&&(depth<100.f)
          && (u+radius>0.f)&&(u-radius<(float)W_IMG)
          && (v+radius>0.f)&&(v-radius<(float)H_IMG);
  float o = vis ? opa[i] : 0.f;
  float ar=a+1e-4f, dr=d+1e-4f;
  float inv=1.f/(ar*dr-b*c_);
  short4 bb = make_short4(1000, -1000, 1000, -1000);    // sentinel: no hit
  char4  bt = make_char4(127, -128, 127, -128);         // tile-unit sentinel
  if (o>0.f) {
    bb.x=(short)truncf(u-radius); bb.y=(short)truncf(u+radius);
    bb.z=(short)truncf(v-radius); bb.w=(short)truncf(v+radius);
    bt.x=(char)(((int)bb.x)>>3); bt.y=(char)(((int)bb.y)>>3);
    bt.z=(char)(((int)bb.z)>>3); bt.w=(char)(((int)bb.w)>>3);
  }
  unsigned hrg = (unsigned)__half_as_ushort(__float2half_rn(col[3*i]))
               | ((unsigned)__half_as_ushort(__float2half_rn(col[3*i+1]))<<16);
  depthU[i] = depth;
  bbhU[i]   = bb;
  bbtU[i]   = bt;
  gaussU[2*i]   = make_float4(u, v, (dr*inv)*HLOG2E,
                              ((-b*inv)+(-c_*inv))*HLOG2E);
  gaussU[2*i+1] = make_float4((ar*inv)*HLOG2E, log2f(o),
                              __uint_as_float(hrg), col[3*i+2]);
}

// ---- kernel 2: single-pass cull + fused rank/gather + prefetched composite
// Block = 16x8 region (2 tiles of 8x8), 16 waves, 2 blocks/CU. R18 champion:
// 4B tile-unit cull bbox (exact for 8-aligned regions), depth loaded
// coalesced with the bbox batch, gather loads issued before the rank loop.
__global__ __launch_bounds__(1024) void render(
    const char4* __restrict__ bbtU, const short4* __restrict__ bbhU,
    const float4* __restrict__ gaussU, const float* __restrict__ depthU,
    float* __restrict__ out)
{
  __shared__ __align__(16) unsigned long long keys[CAP];    // 8 KB
  __shared__ float4 gp[CAP*2];                              // 32 KB
  __shared__ short4 bbh[CAP];                               // 8 KB
  __shared__ float4 res[16][64];                            // 16 KB
  __shared__ int lcnt;

  const int tid = threadIdx.x, wv = tid>>6, lane = tid&63;
  const int bid = (int)((blockIdx.x * 331u) & 511u);   // spread heavy regions
  const int RX0=(bid&15)*16, RY0=(bid>>4)*8;
  const int rtx0=RX0>>3, rtx1=(RX0+15)>>3, rty=RY0>>3;

  if (tid==0) lcnt=0;
  __syncthreads();

  // ---- cull: 16 waves x 4 chunks; coalesced bbox+depth batch, then
  //      ballot-aggregated LDS-atomic scatter (keys from registers) ----
  {
    char4 bt[4]; float dep[4];
    #pragma unroll
    for (int c4=0;c4<4;c4++) {
      int idx=(wv*4+c4)*64+lane;
      bt[c4]=bbtU[idx];
      dep[c4]=depthU[idx];
    }
    #pragma unroll
    for (int c4=0;c4<4;c4++) {
      int idx=(wv*4+c4)*64+lane;
      bool pred=(bt[c4].y>=rtx0)&&(bt[c4].x<=rtx1)&&(bt[c4].w>=rty)&&(bt[c4].z<=rty);
      unsigned long long m=__ballot(pred);
      if (m) {
        int bse=0;
        if (lane==0) bse=atomicAdd(&lcnt, __popcll(m));
        bse=__shfl(bse,0);
        if (pred) {
          int p=bse+__popcll(m&((1ull<<lane)-1ull));
          if (p<CAP)
            keys[p]=((unsigned long long)__float_as_uint(dep[c4])<<12)
                   |(unsigned)idx;
        }
      }
    }
  }
  __syncthreads();
  const int len = (lcnt<CAP)?lcnt:CAP;

  // ---- fused stable rank + gather; gather loads issued EARLY ----
  if (tid<len) {
    unsigned long long kj=keys[tid];
    int idx=(int)(kj&4095u);
    float4 g0=gaussU[2*idx];          // issue now: latency hides under
    float4 g1=gaussU[2*idx+1];        // the LDS-bound rank loop below
    short4 b0=bbhU[idx];
    int r=0;
    const ulonglong2* k2=(const ulonglong2*)keys;
    int n2=len>>1;
    for(int s2=0;s2<n2;s2++){
      ulonglong2 kv=k2[s2];
      r += (kv.x<kj)+(kv.y<kj);
    }
    if(len&1) r += (keys[len-1]<kj);
    gp[2*r]  =g0;
    gp[2*r+1]=g1;
    bbh[r]   =b0;
  }
  __syncthreads();

  // ---- composite: wave w -> tile t=w>>3, depth-segment s=w&7 ----
  const int t=wv>>3, seg=wv&7;
  const int TX0=RX0+t*8, TY0=RY0, TX1=TX0+7, TY1=TY0+7;
  const int ipx=TX0+(lane&7), ipy=TY0+(lane>>3);
  const float px=(float)ipx, py=(float)ipy;
  const int segLen=(len+7)>>3;
  const int s=seg*segLen;
  int e=s+segLen; if(e>len) e=len;
  float aR=0.f,aG=0.f,aB=0.f,aA=0.f;
  for(int k0=s;k0<e;k0+=64){
    int kk=k0+lane;
    bool ok=false;
    if(kk<e){
      short4 bb=bbh[kk];
      ok=(bb.y>=TX0)&&(bb.x<=TX1)&&(bb.w>=TY0)&&(bb.z<=TY1);
    }
    unsigned long long mm=__ballot(ok);     // tile compaction, order-kept
    if(mm){
      int k=k0+__builtin_ctzll(mm); mm&=mm-1;
      short4 bb=bbh[k];                     // current (broadcast)
      float4 A=gp[2*k], B=gp[2*k+1];
      while(mm){
        int kn=k0+__builtin_ctzll(mm); mm&=mm-1;
        short4 bbn=bbh[kn];                 // prefetch next while computing
        float4 An=gp[2*kn], Bn=gp[2*kn+1];
        float dx=px-A.x, dy=py-A.y;
        float q2=A.z*dx*dx + A.w*dx*dy + B.x*dy*dy;
        bool inside=(ipx>=bb.x)&&(ipx<=bb.y)&&(ipy>=bb.z)&&(ipy<=bb.w);
        float ex=__builtin_amdgcn_exp2f(B.y-q2);
        float alpha= inside ? ex : 0.f;
        float w=alpha*(1.f-aA);
        unsigned hrg=__float_as_uint(B.z);
        float cR=__half2float(__ushort_as_half((unsigned short)(hrg&0xFFFFu)));
        float cG=__half2float(__ushort_as_half((unsigned short)(hrg>>16)));
        aR+=w*cR; aG+=w*cG; aB+=w*B.w; aA+=w;
        bb=bbn; A=An; B=Bn;
      }
      float dx=px-A.x, dy=py-A.y;
      float q2=A.z*dx*dx + A.w*dx*dy + B.x*dy*dy;
      bool inside=(ipx>=bb.x)&&(ipx<=bb.y)&&(ipy>=bb.z)&&(ipy<=bb.w);
      float ex=__builtin_amdgcn_exp2f(B.y-q2);
      float alpha= inside ? ex : 0.f;
      float w=alpha*(1.f-aA);
      unsigned hrg=__float_as_uint(B.z);
      float cR=__half2float(__ushort_as_half((unsigned short)(hrg&0xFFFFu)));
      float cG=__half2float(__ushort_as_half((unsigned short)(hrg>>16)));
      aR+=w*cR; aG+=w*cG; aB+=w*B.w; aA+=w;
    }
    if(__ballot(aA<=0.9999f)==0ull) break;  // residual < 1e-4
  }
  res[wv][lane]=make_float4(aR,aG,aB,aA);
  __syncthreads();

  // ---- ordered 8-way fold per tile, store ----
  if(seg==0){
    float4 P=res[wv][lane];
    #pragma unroll
    for(int w=1;w<8;w++){
      float4 Q=res[wv+w][lane];
      float tr_=1.f-P.w;
      P.x+=tr_*Q.x; P.y+=tr_*Q.y; P.z+=tr_*Q.z; P.w+=tr_*Q.w;
    }
    out[0*H_IMG*W_IMG + ipy*W_IMG + ipx]=P.x;
    out[1*H_IMG*W_IMG + ipy*W_IMG + ipx]=P.y;
    out[2*H_IMG*W_IMG + ipy*W_IMG + ipx]=P.z;
  }
}

extern "C" void kernel_launch(void* const* d_in, const int* in_sizes, int n_in,
                              void* d_out, int out_size, void* d_ws, size_t ws_size,
                              hipStream_t stream)
{
  const float* pos=(const float*)d_in[0];
  const float* scl=(const float*)d_in[1];
  const float* rot=(const float*)d_in[2];
  const float* col=(const float*)d_in[3];
  const float* opa=(const float*)d_in[4];
  const float* vm =(const float*)d_in[5];
  float* out=(float*)d_out;
  char* ws=(char*)d_ws;
  float4* gaussU=(float4*)(ws);               // 128 KB
  short4* bbhU  =(short4*)(ws + 128*1024);    // 32 KB
  float*  depthU=(float*) (ws + 160*1024);    // 16 KB
  char4*  bbtU  =(char4*) (ws + 176*1024);    // 16 KB
  prep<<<N_G/64, 64, 0, stream>>>(pos,scl,rot,col,opa,vm,gaussU,bbhU,depthU,bbtU);
  render<<<512, 1024, 0, stream>>>(bbtU,bbhU,gaussU,depthU,out);
}